// Round 21
// baseline (134.786 us; speedup 1.0000x reference)
//
#include <hip/hip_runtime.h>
#include <hip/hip_bf16.h>

// GCN: out = (segment_sum over edges+selfloops of norm * emb[src]) @ W, gathered at `nodes`.
// Round 21: B-RESIDENT-IN-LDS gemm. All block-synchronous pipeline variants converged
// at ~130 us with every pipe idle. Root causes across r11-r20: barriers couple waves;
// removing them exposed per-step B reloads. Fix both: stage ALL of wt (128 KB bf16
// frag-packed) in LDS once per block (fits 160 KB phys), then 16 waves free-run their
// own A rows global->regs (depth-2 static prefetch), ZERO K-loop barriers, B via
// conflict-free lane-linear ds_read_b128. Per-step VMEM: 24 wave-instrs -> 2.
// 256-row blocks, 1024 thr, 1 block/CU; degfill (LPT-second) backfills the tail.

constexpr int KDIM = 512;   // embedding dim
constexpr int CDIM = 128;   // output channels
constexpr int CAPB = 64;    // bucket capacity per slot (Poisson(16); P(X>=64)~1e-19)
constexpr int CAPO = 16;    // max duplicate output rows per node

typedef __attribute__((ext_vector_type(8))) short short8;   // 8 bf16 (A/B frag)
typedef __attribute__((ext_vector_type(4))) float f32x4;    // C/D frag

static __device__ __forceinline__ unsigned short f2bf(float f) {
    __hip_bfloat16 b = __float2bfloat16(f);          // RNE, compiler-optimized
    return *reinterpret_cast<unsigned short*>(&b);
}
static __device__ __forceinline__ float bf2f(unsigned short b) {
    return __uint_as_float(((unsigned)b) << 16);
}

// ---- fused init + wprep: deg=0, tmap=-1, cur=0, ocnt=0, ucount=0, wt=pack(W) ----
__global__ void k_init(int* __restrict__ deg, int* __restrict__ tmap,
                       int* __restrict__ cur, int* __restrict__ ocnt,
                       int* __restrict__ ucount,
                       const float* __restrict__ W, unsigned short* __restrict__ wt,
                       int N, int n) {
    int i = blockIdx.x * blockDim.x + threadIdx.x;
    if (i < N) { deg[i] = 0; tmap[i] = -1; }
    if (i < n) { cur[i] = 0; ocnt[i] = 0; }
    if (i == 0) *ucount = 0;
    if (i < 65536) {
        int j  = i & 7;
        int l  = (i >> 3) & 63;
        int st = i >> 9;
        int t  = st & 7, s = st >> 3;
        int k  = s * 32 + (l >> 4) * 8 + j;
        int c  = t * 16 + (l & 15);
        wt[i] = f2bf(W[(size_t)k * CDIM + c]);
    }
}

// ---- unique-target compaction: tmap[node] = slot or -1 ----
__global__ void k_targets(const int* __restrict__ nodes, int n,
                          int* __restrict__ tmap, int* __restrict__ tlist,
                          int* __restrict__ ucount) {
    int i = blockIdx.x * blockDim.x + threadIdx.x;
    if (i >= n) return;
    int v = nodes[i];
    if (atomicCAS(&tmap[v], -1, -2) == -1) {   // claim
        int slot = atomicAdd(ucount, 1);
        tlist[slot] = v;
        tmap[v] = slot;                        // only the claimer writes
    }
}

// ---- mega kernel: gemm blocks [0,GB), degfill [GB,GB+DB), outmap [GB+DB,+OB) ----
__global__ __launch_bounds__(1024, 1)
void k_main(const float* __restrict__ emb, const unsigned short* __restrict__ wt,
            unsigned short* __restrict__ h, int N,
            const int* __restrict__ erow, const int* __restrict__ ecol, int E,
            int* __restrict__ deg, const int* __restrict__ tmap,
            int* __restrict__ cur, int* __restrict__ ebuf,
            const int* __restrict__ nodes, int n,
            int* __restrict__ ocnt, int* __restrict__ olist,
            int GB, int DB) {
    int bid = (int)blockIdx.x;
    int tid = threadIdx.x;
    if (bid >= GB + DB) {
        // ================= outmap =================
        int i = (bid - GB - DB) * 1024 + tid;
        if (i >= n) return;
        int slot = tmap[nodes[i]];             // always >= 0 after k_targets
        int p = atomicAdd(&ocnt[slot], 1);
        if (p < CAPO) olist[slot * CAPO + p] = i;
        return;
    }
    if (bid >= GB) {
        // ================= degfill =================
        int t = (bid - GB) * 1024 + tid;
        int base = t * 4;
        if (base >= E) return;
        if (base + 4 <= E) {
            int4 c = *reinterpret_cast<const int4*>(ecol + base);
            atomicAdd(&deg[c.x], 1);
            atomicAdd(&deg[c.y], 1);
            atomicAdd(&deg[c.z], 1);
            atomicAdd(&deg[c.w], 1);
            int s0 = tmap[c.x], s1 = tmap[c.y], s2 = tmap[c.z], s3 = tmap[c.w];
            if ((s0 >= 0) | (s1 >= 0) | (s2 >= 0) | (s3 >= 0)) {
                int4 r = *reinterpret_cast<const int4*>(erow + base);
                if (s0 >= 0) { int p = atomicAdd(&cur[s0], 1); if (p < CAPB) ebuf[s0 * CAPB + p] = r.x; }
                if (s1 >= 0) { int p = atomicAdd(&cur[s1], 1); if (p < CAPB) ebuf[s1 * CAPB + p] = r.y; }
                if (s2 >= 0) { int p = atomicAdd(&cur[s2], 1); if (p < CAPB) ebuf[s2 * CAPB + p] = r.z; }
                if (s3 >= 0) { int p = atomicAdd(&cur[s3], 1); if (p < CAPB) ebuf[s3 * CAPB + p] = r.w; }
            }
        } else {
            for (int i = base; i < E; ++i) {
                int c = ecol[i];
                atomicAdd(&deg[c], 1);
                int s = tmap[c];
                if (s >= 0) { int p = atomicAdd(&cur[s], 1); if (p < CAPB) ebuf[s * CAPB + p] = erow[i]; }
            }
        }
        return;
    }
    // ================= gemm: B fully LDS-resident, barrier-free A stream =================
    // 16 waves x (16 rows x 128 cols) = 256 rows/block. B = all 16 K-steps of wt
    // (65536 bf16 = 128 KB LDS), staged once. A: each wave streams its own 16 rows
    // from global into registers (depth-2 static prefetch), no K-loop barriers.
    extern __shared__ char smem[];
    unsigned short* sBall = (unsigned short*)smem;           // 128 KB
    int lane = tid & 63;
    int wid  = tid >> 6;                       // wave 0..15
    int row0 = bid * 256;

    // stage ALL of B: 8192 x 16B chunks / 1024 thr = 8 each, lane-linear dest
    #pragma unroll
    for (int p = 0; p < 8; ++p) {
        int i = p * 1024 + tid;
        const unsigned short* g = wt + (size_t)i * 8;
        unsigned short* l = sBall + (size_t)i * 8;
        __builtin_amdgcn_global_load_lds(
            (const __attribute__((address_space(1))) void*)g,
            (__attribute__((address_space(3))) void*)l, 16, 0, 0);
    }
    asm volatile("s_waitcnt vmcnt(0)" ::: "memory");
    __builtin_amdgcn_s_barrier();

    int row = row0 + wid * 16 + (lane & 15);
    if (row >= N) row = N - 1;                 // clamp loads; stores guarded below
    int kq = lane >> 4;                        // k-quarter 0..3
    const float* abase = emb + (size_t)row * KDIM + kq * 8;

    f32x4 acc[8];
    #pragma unroll
    for (int t = 0; t < 8; ++t) acc[t] = (f32x4){0.f, 0.f, 0.f, 0.f};

    float4 apf0[2], apf1[2];                   // depth-2 prefetch (static idx via unroll)
    #pragma unroll
    for (int s = 0; s < 2; ++s) {
        apf0[s] = *reinterpret_cast<const float4*>(abase + s * 32);
        apf1[s] = *reinterpret_cast<const float4*>(abase + s * 32 + 4);
    }

    const short8* Bb = reinterpret_cast<const short8*>(sBall);
    #pragma unroll
    for (int ks = 0; ks < 16; ++ks) {
        float4 v0 = apf0[ks & 1];
        float4 v1 = apf1[ks & 1];
        if (ks + 2 < 16) {                     // refill slot 2 steps ahead
            apf0[ks & 1] = *reinterpret_cast<const float4*>(abase + (ks + 2) * 32);
            apf1[ks & 1] = *reinterpret_cast<const float4*>(abase + (ks + 2) * 32 + 4);
        }
        short8 af;
        af[0] = (short)f2bf(v0.x); af[1] = (short)f2bf(v0.y);
        af[2] = (short)f2bf(v0.z); af[3] = (short)f2bf(v0.w);
        af[4] = (short)f2bf(v1.x); af[5] = (short)f2bf(v1.y);
        af[6] = (short)f2bf(v1.z); af[7] = (short)f2bf(v1.w);
        const short8* wp = Bb + (size_t)(ks * 8) * 64 + lane;  // lane-linear, conflict-free
        #pragma unroll
        for (int tt = 0; tt < 8; ++tt) {
            short8 bf = wp[tt * 64];
            acc[tt] = __builtin_amdgcn_mfma_f32_16x16x32_bf16(af, bf, acc[tt], 0, 0, 0);
        }
    }

    // ---- epilogue: C -> LDS (D layout: col=lane&15, row=(lane>>4)*4+reg) -> h ----
    __syncthreads();                           // all waves done reading B; reuse smem
    unsigned short* sC = (unsigned short*)smem;             // 256 x 128 bf16 = 64 KB
    int rl0 = wid * 16 + (lane >> 4) * 4;
    int cl0 = lane & 15;
    #pragma unroll
    for (int tt = 0; tt < 8; ++tt)
        #pragma unroll
        for (int j = 0; j < 4; ++j)
            sC[(rl0 + j) * 128 + cl0 + tt * 16] = f2bf(acc[tt][j]);
    __syncthreads();
    #pragma unroll
    for (int c = 0; c < 4; ++c) {              // 4096 x 16B chunks, coalesced
        int i = c * 1024 + tid;
        int r2 = i >> 4, off = i & 15;
        int r = row0 + r2;
        if (r < N)
            *reinterpret_cast<short8*>(h + (size_t)r * CDIM + off * 8) =
                *reinterpret_cast<const short8*>(sC + r2 * 128 + off * 8);
    }
}

// ---- per-target aggregation over h: quarter-wave 4-row-parallel, UNIFORM trips ----
__global__ __launch_bounds__(256)
void k_agg(const unsigned short* __restrict__ h, const int* __restrict__ deg,
           const int* __restrict__ tlist, const int* __restrict__ cur,
           const int* __restrict__ ebuf, const int* __restrict__ ucount,
           const int* __restrict__ ocnt, const int* __restrict__ olist,
           float* __restrict__ out) {
    int u = *ucount;
    int slot = blockIdx.x * 4 + (threadIdx.x >> 6);
    if (slot >= u) return;                 // wave-uniform exit
    int lane = threadIdx.x & 63;
    int e = min(cur[slot], CAPB);
    int myi = 0; float myw = 0.f;
    if (lane < e) {
        myi = ebuf[(size_t)slot * CAPB + lane];          // coalesced
        myw = rsqrtf((float)(deg[myi] + 1));
    }
    int q  = lane >> 4;                    // source substream 0..3
    int cl = lane & 15;                    // col-chunk: cols [cl*8, cl*8+8)
    float acc[8];
    #pragma unroll
    for (int x = 0; x < 8; ++x) acc[x] = 0.f;
    int trips = (e + 3) >> 2;              // wave-uniform trip count
    for (int t = 0; t < trips; ++t) {
        int j = t * 4 + q;
        int   src = __shfl(myi, j, 64);    // all lanes active -> sources live
        float w   = __shfl(myw, j, 64);    // w = 0 when j >= e
        short8 v = *reinterpret_cast<const short8*>(h + (size_t)src * CDIM + cl * 8);
        #pragma unroll
        for (int x = 0; x < 8; ++x)
            acc[x] += w * bf2f((unsigned short)v[x]);
    }
    #pragma unroll
    for (int x = 0; x < 8; ++x) {
        acc[x] += __shfl_xor(acc[x], 16, 64);
        acc[x] += __shfl_xor(acc[x], 32, 64);
    }
    int t = tlist[slot];
    float dt = rsqrtf((float)(deg[t] + 1));
    short8 v = *reinterpret_cast<const short8*>(h + (size_t)t * CDIM + cl * 8);
    float4 r0, r1;
    r0.x = dt * (acc[0] + dt * bf2f((unsigned short)v[0]));
    r0.y = dt * (acc[1] + dt * bf2f((unsigned short)v[1]));
    r0.z = dt * (acc[2] + dt * bf2f((unsigned short)v[2]));
    r0.w = dt * (acc[3] + dt * bf2f((unsigned short)v[3]));
    r1.x = dt * (acc[4] + dt * bf2f((unsigned short)v[4]));
    r1.y = dt * (acc[5] + dt * bf2f((unsigned short)v[5]));
    r1.z = dt * (acc[6] + dt * bf2f((unsigned short)v[6]));
    r1.w = dt * (acc[7] + dt * bf2f((unsigned short)v[7]));
    if (q == 0) {
        int cnt = min(ocnt[slot], CAPO);
        for (int qq = 0; qq < cnt; ++qq) {
            int i = olist[slot * CAPO + qq];
            float* op = out + (size_t)i * CDIM + cl * 8;
            *reinterpret_cast<float4*>(op)     = r0;
            *reinterpret_cast<float4*>(op + 4) = r1;
        }
    }
}

extern "C" void kernel_launch(void* const* d_in, const int* in_sizes, int n_in,
                              void* d_out, int out_size, void* d_ws, size_t ws_size,
                              hipStream_t stream) {
    const int*   nodes = (const int*)d_in[0];
    const int*   eidx  = (const int*)d_in[1];
    const float* emb   = (const float*)d_in[2];
    const float* W     = (const float*)d_in[3];
    float*       out   = (float*)d_out;

    int n = in_sizes[0];             // 10000
    int E = in_sizes[1] / 2;         // 1,600,000
    int N = in_sizes[2] / KDIM;      // 100,000
    const int* erow = eidx;          // sources
    const int* ecol = eidx + E;      // targets

    // workspace carve (~30 MB total)
    char* ws = (char*)d_ws;
    size_t o = 0;
    auto carve = [&](size_t bytes) {
        char* p = ws + o;
        o = (o + bytes + 255) & ~(size_t)255;
        return p;
    };
    int* deg    = (int*)carve((size_t)N * 4);
    int* tmap   = (int*)carve((size_t)N * 4);
    int* tlist  = (int*)carve((size_t)n * 4);
    int* cur    = (int*)carve((size_t)n * 4);
    int* ocnt   = (int*)carve((size_t)n * 4);
    int* olist  = (int*)carve((size_t)n * CAPO * 4);
    int* ucount = (int*)carve(4);
    int* ebuf   = (int*)carve((size_t)n * CAPB * 4);
    unsigned short* wt = (unsigned short*)carve((size_t)16 * 8 * 64 * 8 * 2);   // 128 KB
    unsigned short* h  = (unsigned short*)carve((size_t)N * CDIM * 2);          // 25.6 MB
    (void)ws_size; (void)n_in; (void)out_size;

    hipFuncSetAttribute(reinterpret_cast<const void*>(k_main),
                        hipFuncAttributeMaxDynamicSharedMemorySize, 131072);

    int GB = (N + 255) / 256;        // gemm blocks     = 391 (256 rows each)
    int DB = (E + 4095) / 4096;      // degfill blocks  = 391 (1024 thr x 4 edges)
    int OB = (n + 1023) / 1024;      // outmap blocks   = 10
    k_init   <<<(N + 255) / 256, 256, 0, stream>>>(deg, tmap, cur, ocnt, ucount, W, wt, N, n);
    k_targets<<<(n + 255) / 256, 256, 0, stream>>>(nodes, n, tmap, tlist, ucount);
    k_main   <<<GB + DB + OB, 1024, 131072, stream>>>(emb, wt, h, N,
                                                      erow, ecol, E, deg, tmap, cur, ebuf,
                                                      nodes, n, ocnt, olist, GB, DB);
    k_agg    <<<(n + 3) / 4, 256, 0, stream>>>(h, deg, tlist, cur, ebuf, ucount,
                                               ocnt, olist, out);
}

// Round 22
// 128.330 us; speedup vs baseline: 1.0503x; 1.0503x over previous
//
#include <hip/hip_runtime.h>
#include <hip/hip_bf16.h>

// GCN: out = (segment_sum over edges+selfloops of norm * emb[src]) @ W, gathered at `nodes`.
// Round 22: XCD-PRIVATIZED deg atomics. Seven gemm schedules all landed 130-143 with
// every pipe <5% busy -> the schedule-invariant degfill role (1.75M device-scope
// atomics, cross-XCD line ping-pong; WRITE_SIZE 84MB vs 28MB real) is the bottleneck.
// deg -> 8 per-XCD copies (block bid&7 ~ its XCD via round-robin dispatch); new k_dsum
// reduces copies -> dinv = rsqrtf(sum+1). Gemm/k_agg = r18 (best, 130.6); cur/ebuf
// atomics (10x fewer) left as-is for attribution.

constexpr int KDIM = 512;   // embedding dim
constexpr int CDIM = 128;   // output channels
constexpr int CAPB = 64;    // bucket capacity per slot (Poisson(16); P(X>=64)~1e-19)
constexpr int CAPO = 16;    // max duplicate output rows per node
constexpr int NCPY = 8;     // deg privatization copies (~1 per XCD)

typedef __attribute__((ext_vector_type(8))) short short8;   // 8 bf16 (A/B frag)
typedef __attribute__((ext_vector_type(4))) float f32x4;    // C/D frag

static __device__ __forceinline__ unsigned short f2bf(float f) {
    __hip_bfloat16 b = __float2bfloat16(f);          // RNE, compiler-optimized
    return *reinterpret_cast<unsigned short*>(&b);
}
static __device__ __forceinline__ float bf2f(unsigned short b) {
    return __uint_as_float(((unsigned)b) << 16);
}

// ---- fused init + wprep: deg8=0, tmap=-1, cur=0, ocnt=0, ucount=0, wt=pack(W) ----
__global__ void k_init(int* __restrict__ deg8, int* __restrict__ tmap,
                       int* __restrict__ cur, int* __restrict__ ocnt,
                       int* __restrict__ ucount,
                       const float* __restrict__ W, unsigned short* __restrict__ wt,
                       int N, int n) {
    int i = blockIdx.x * blockDim.x + threadIdx.x;
    if (i < NCPY * N) deg8[i] = 0;
    if (i < N) tmap[i] = -1;
    if (i < n) { cur[i] = 0; ocnt[i] = 0; }
    if (i == 0) *ucount = 0;
    if (i < 65536) {
        int j  = i & 7;
        int l  = (i >> 3) & 63;
        int st = i >> 9;
        int t  = st & 7, s = st >> 3;
        int k  = s * 32 + (l >> 4) * 8 + j;
        int c  = t * 16 + (l & 15);
        wt[i] = f2bf(W[(size_t)k * CDIM + c]);
    }
}

// ---- unique-target compaction: tmap[node] = slot or -1 ----
__global__ void k_targets(const int* __restrict__ nodes, int n,
                          int* __restrict__ tmap, int* __restrict__ tlist,
                          int* __restrict__ ucount) {
    int i = blockIdx.x * blockDim.x + threadIdx.x;
    if (i >= n) return;
    int v = nodes[i];
    if (atomicCAS(&tmap[v], -1, -2) == -1) {   // claim
        int slot = atomicAdd(ucount, 1);
        tlist[slot] = v;
        tmap[v] = slot;                        // only the claimer writes
    }
}

// ---- reduce privatized copies -> dinv = rsqrt(deg + 1) ----
__global__ void k_dsum(const int* __restrict__ deg8, float* __restrict__ dinv, int N) {
    int i = blockIdx.x * blockDim.x + threadIdx.x;
    if (i >= N) return;
    int s = 0;
    #pragma unroll
    for (int x = 0; x < NCPY; ++x) s += deg8[(size_t)x * N + i];
    dinv[i] = rsqrtf((float)(s + 1));
}

// ---- mega kernel: gemm blocks [0,GB), degfill [GB,GB+DB), outmap [GB+DB,+OB) ----
__global__ __launch_bounds__(512, 2)
void k_main(const float* __restrict__ emb, const unsigned short* __restrict__ wt,
            unsigned short* __restrict__ h, int N,
            const int* __restrict__ erow, const int* __restrict__ ecol, int E,
            int* __restrict__ deg8, const int* __restrict__ tmap,
            int* __restrict__ cur, int* __restrict__ ebuf,
            const int* __restrict__ nodes, int n,
            int* __restrict__ ocnt, int* __restrict__ olist,
            int GB, int DB) {
    int bid = (int)blockIdx.x;
    if (bid >= GB + DB) {
        // ================= outmap =================
        int i = (bid - GB - DB) * 512 + threadIdx.x;
        if (i >= n) return;
        int slot = tmap[nodes[i]];             // always >= 0 after k_targets
        int p = atomicAdd(&ocnt[slot], 1);
        if (p < CAPO) olist[slot * CAPO + p] = i;
        return;
    }
    if (bid >= GB) {
        // ================= degfill (XCD-private deg copy) =================
        int* dp = deg8 + (size_t)(bid & (NCPY - 1)) * N;   // round-robin ~ XCD-local
        int t = (bid - GB) * 512 + threadIdx.x;
        int base = t * 4;
        if (base >= E) return;
        if (base + 4 <= E) {
            int4 c = *reinterpret_cast<const int4*>(ecol + base);
            atomicAdd(&dp[c.x], 1);
            atomicAdd(&dp[c.y], 1);
            atomicAdd(&dp[c.z], 1);
            atomicAdd(&dp[c.w], 1);
            int s0 = tmap[c.x], s1 = tmap[c.y], s2 = tmap[c.z], s3 = tmap[c.w];
            if ((s0 >= 0) | (s1 >= 0) | (s2 >= 0) | (s3 >= 0)) {
                int4 r = *reinterpret_cast<const int4*>(erow + base);
                if (s0 >= 0) { int p = atomicAdd(&cur[s0], 1); if (p < CAPB) ebuf[s0 * CAPB + p] = r.x; }
                if (s1 >= 0) { int p = atomicAdd(&cur[s1], 1); if (p < CAPB) ebuf[s1 * CAPB + p] = r.y; }
                if (s2 >= 0) { int p = atomicAdd(&cur[s2], 1); if (p < CAPB) ebuf[s2 * CAPB + p] = r.z; }
                if (s3 >= 0) { int p = atomicAdd(&cur[s3], 1); if (p < CAPB) ebuf[s3 * CAPB + p] = r.w; }
            }
        } else {
            for (int i = base; i < E; ++i) {
                int c = ecol[i];
                atomicAdd(&dp[c], 1);
                int s = tmap[c];
                if (s >= 0) { int p = atomicAdd(&cur[s], 1); if (p < CAPB) ebuf[s * CAPB + p] = erow[i]; }
            }
        }
        return;
    }
    // ================= gemm (r18 verbatim) =================
    // 8 waves x (16 rows x 128 cols); tile 128x128, BK=32, 16 K-steps, 3 LDS buffers.
    extern __shared__ char smem[];
    float*          sA = (float*)smem;                        // 3 x 4096 f32
    unsigned short* sB = (unsigned short*)(smem + 3 * 16384); // 3 x 4096 bf16
    int tid  = threadIdx.x;
    int lane = tid & 63;
    int wid  = tid >> 6;            // row-group 0..7 (16 rows each)
    int row0 = bid * 128;

    auto stage = [&](int buf, int kc) {
        #pragma unroll
        for (int p = 0; p < 2; ++p) {          // A: 1024 x 16B chunks
            int i = p * 512 + tid;
            int row = i >> 3, chunk = i & 7;
            int swz = chunk ^ (row & 7);       // pre-swizzled source, linear LDS
            int rg = row0 + row; if (rg >= N) rg = N - 1;
            const float* g = emb + (size_t)rg * KDIM + kc * 32 + swz * 4;
            float* l = sA + buf * 4096 + i * 4;
            __builtin_amdgcn_global_load_lds(
                (const __attribute__((address_space(1))) void*)g,
                (__attribute__((address_space(3))) void*)l, 16, 0, 0);
        }
        {                                      // B: 512 x 16B chunks
            const unsigned short* g = wt + (size_t)kc * 4096 + tid * 8;
            unsigned short* l = sB + buf * 4096 + tid * 8;
            __builtin_amdgcn_global_load_lds(
                (const __attribute__((address_space(1))) void*)g,
                (__attribute__((address_space(3))) void*)l, 16, 0, 0);
        }
    };

    f32x4 acc[8];
    #pragma unroll
    for (int t = 0; t < 8; ++t) acc[t] = (f32x4){0.f, 0.f, 0.f, 0.f};

    int arow = wid * 16 + (lane & 15);         // local A row
    int kq   = lane >> 4;                      // k-quarter 0..3

    auto compute = [&](int buf) {
        const float*          Ab = sA + buf * 4096;
        const unsigned short* Bb = sB + buf * 4096;
        int c0 = kq * 2;
        int s0 = c0 ^ (arow & 7);
        int s1 = (c0 + 1) ^ (arow & 7);
        float4 v0 = *reinterpret_cast<const float4*>(Ab + arow * 32 + s0 * 4);
        float4 v1 = *reinterpret_cast<const float4*>(Ab + arow * 32 + s1 * 4);
        short8 af;
        af[0] = (short)f2bf(v0.x); af[1] = (short)f2bf(v0.y);
        af[2] = (short)f2bf(v0.z); af[3] = (short)f2bf(v0.w);
        af[4] = (short)f2bf(v1.x); af[5] = (short)f2bf(v1.y);
        af[6] = (short)f2bf(v1.z); af[7] = (short)f2bf(v1.w);
        #pragma unroll
        for (int tt = 0; tt < 8; ++tt) {
            short8 bf = *reinterpret_cast<const short8*>(Bb + ((size_t)(tt * 64 + lane)) * 8);
            acc[tt] = __builtin_amdgcn_mfma_f32_16x16x32_bf16(af, bf, acc[tt], 0, 0, 0);
        }
    };

    stage(0, 0); stage(1, 1); stage(2, 2);     // prologue: 3 tiles in flight (9 loads)

    for (int kc = 0; kc < 14; ++kc) {          // steady state: 2 tiles always in flight
        if (kc > 0) stage((kc + 2) % 3, kc + 2);
        asm volatile("s_waitcnt vmcnt(6)" ::: "memory");   // tile kc ready
        __builtin_amdgcn_s_barrier();
        asm volatile("" ::: "memory");
        compute(kc % 3);
        asm volatile("" ::: "memory");
        __builtin_amdgcn_s_barrier();          // frees buf kc%3
    }
    asm volatile("s_waitcnt vmcnt(3)" ::: "memory");       // kc = 14
    __builtin_amdgcn_s_barrier();
    asm volatile("" ::: "memory");
    compute(2);
    asm volatile("" ::: "memory");
    __builtin_amdgcn_s_barrier();
    asm volatile("s_waitcnt vmcnt(0)" ::: "memory");       // kc = 15
    __builtin_amdgcn_s_barrier();
    asm volatile("" ::: "memory");
    compute(0);

    // ---- epilogue: C -> LDS (D layout: col=lane&15, row=(lane>>4)*4+reg) -> h ----
    __syncthreads();                           // all buffer reads done; reuse smem
    unsigned short* sC = (unsigned short*)smem;             // 128 x 128 bf16 = 32 KB
    int rl0 = wid * 16 + (lane >> 4) * 4;
    int cl0 = lane & 15;
    #pragma unroll
    for (int tt = 0; tt < 8; ++tt)
        #pragma unroll
        for (int j = 0; j < 4; ++j)
            sC[(rl0 + j) * 128 + cl0 + tt * 16] = f2bf(acc[tt][j]);
    __syncthreads();
    #pragma unroll
    for (int c = 0; c < 4; ++c) {              // 2048 x 16B chunks, coalesced
        int i = c * 512 + tid;
        int row = i >> 4, off = i & 15;
        int r = row0 + row;
        if (r < N)
            *reinterpret_cast<short8*>(h + (size_t)r * CDIM + off * 8) =
                *reinterpret_cast<const short8*>(sC + row * 128 + off * 8);
    }
}

// ---- per-target aggregation over h: quarter-wave 4-row-parallel, UNIFORM trips ----
__global__ __launch_bounds__(256)
void k_agg(const unsigned short* __restrict__ h, const float* __restrict__ dinv,
           const int* __restrict__ tlist, const int* __restrict__ cur,
           const int* __restrict__ ebuf, const int* __restrict__ ucount,
           const int* __restrict__ ocnt, const int* __restrict__ olist,
           float* __restrict__ out) {
    int u = *ucount;
    int slot = blockIdx.x * 4 + (threadIdx.x >> 6);
    if (slot >= u) return;                 // wave-uniform exit
    int lane = threadIdx.x & 63;
    int e = min(cur[slot], CAPB);
    int myi = 0; float myw = 0.f;
    if (lane < e) {
        myi = ebuf[(size_t)slot * CAPB + lane];          // coalesced
        myw = dinv[myi];                                 // precomputed rsqrt
    }
    int q  = lane >> 4;                    // source substream 0..3
    int cl = lane & 15;                    // col-chunk: cols [cl*8, cl*8+8)
    float acc[8];
    #pragma unroll
    for (int x = 0; x < 8; ++x) acc[x] = 0.f;
    int trips = (e + 3) >> 2;              // wave-uniform trip count
    for (int t = 0; t < trips; ++t) {
        int j = t * 4 + q;
        int   src = __shfl(myi, j, 64);    // all lanes active -> sources live
        float w   = __shfl(myw, j, 64);    // w = 0 when j >= e
        short8 v = *reinterpret_cast<const short8*>(h + (size_t)src * CDIM + cl * 8);
        #pragma unroll
        for (int x = 0; x < 8; ++x)
            acc[x] += w * bf2f((unsigned short)v[x]);
    }
    #pragma unroll
    for (int x = 0; x < 8; ++x) {
        acc[x] += __shfl_xor(acc[x], 16, 64);
        acc[x] += __shfl_xor(acc[x], 32, 64);
    }
    int t = tlist[slot];
    float dt = dinv[t];
    short8 v = *reinterpret_cast<const short8*>(h + (size_t)t * CDIM + cl * 8);
    float4 r0, r1;
    r0.x = dt * (acc[0] + dt * bf2f((unsigned short)v[0]));
    r0.y = dt * (acc[1] + dt * bf2f((unsigned short)v[1]));
    r0.z = dt * (acc[2] + dt * bf2f((unsigned short)v[2]));
    r0.w = dt * (acc[3] + dt * bf2f((unsigned short)v[3]));
    r1.x = dt * (acc[4] + dt * bf2f((unsigned short)v[4]));
    r1.y = dt * (acc[5] + dt * bf2f((unsigned short)v[5]));
    r1.z = dt * (acc[6] + dt * bf2f((unsigned short)v[6]));
    r1.w = dt * (acc[7] + dt * bf2f((unsigned short)v[7]));
    if (q == 0) {
        int cnt = min(ocnt[slot], CAPO);
        for (int qq = 0; qq < cnt; ++qq) {
            int i = olist[slot * CAPO + qq];
            float* op = out + (size_t)i * CDIM + cl * 8;
            *reinterpret_cast<float4*>(op)     = r0;
            *reinterpret_cast<float4*>(op + 4) = r1;
        }
    }
}

extern "C" void kernel_launch(void* const* d_in, const int* in_sizes, int n_in,
                              void* d_out, int out_size, void* d_ws, size_t ws_size,
                              hipStream_t stream) {
    const int*   nodes = (const int*)d_in[0];
    const int*   eidx  = (const int*)d_in[1];
    const float* emb   = (const float*)d_in[2];
    const float* W     = (const float*)d_in[3];
    float*       out   = (float*)d_out;

    int n = in_sizes[0];             // 10000
    int E = in_sizes[1] / 2;         // 1,600,000
    int N = in_sizes[2] / KDIM;      // 100,000
    const int* erow = eidx;          // sources
    const int* ecol = eidx + E;      // targets

    // workspace carve (~33 MB total; ws is ~800 MB)
    char* ws = (char*)d_ws;
    size_t o = 0;
    auto carve = [&](size_t bytes) {
        char* p = ws + o;
        o = (o + bytes + 255) & ~(size_t)255;
        return p;
    };
    int*   deg8  = (int*)carve((size_t)NCPY * N * 4);    // 3.2 MB
    float* dinv  = (float*)carve((size_t)N * 4);
    int*   tmap  = (int*)carve((size_t)N * 4);
    int*   tlist = (int*)carve((size_t)n * 4);
    int*   cur   = (int*)carve((size_t)n * 4);
    int*   ocnt  = (int*)carve((size_t)n * 4);
    int*   olist = (int*)carve((size_t)n * CAPO * 4);
    int*   ucount= (int*)carve(4);
    int*   ebuf  = (int*)carve((size_t)n * CAPB * 4);
    unsigned short* wt = (unsigned short*)carve((size_t)16 * 8 * 64 * 8 * 2);   // 128 KB
    unsigned short* h  = (unsigned short*)carve((size_t)N * CDIM * 2);          // 25.6 MB
    (void)ws_size; (void)n_in; (void)out_size;

    hipFuncSetAttribute(reinterpret_cast<const void*>(k_main),
                        hipFuncAttributeMaxDynamicSharedMemorySize, 73728);

    int GB = (N + 127) / 128;        // gemm blocks     = 782
    int DB = (E + 2047) / 2048;      // degfill blocks  = 782 (512 thr x 4 edges)
    int OB = (n + 511) / 512;        // outmap blocks   = 20
    k_init   <<<(NCPY * N + 255) / 256, 256, 0, stream>>>(deg8, tmap, cur, ocnt, ucount,
                                                          W, wt, N, n);
    k_targets<<<(n + 255) / 256, 256, 0, stream>>>(nodes, n, tmap, tlist, ucount);
    k_main   <<<GB + DB + OB, 512, 73728, stream>>>(emb, wt, h, N,
                                                    erow, ecol, E, deg8, tmap, cur, ebuf,
                                                    nodes, n, ocnt, olist, GB, DB);
    k_dsum   <<<(N + 255) / 256, 256, 0, stream>>>(deg8, dinv, N);
    k_agg    <<<(n + 3) / 4, 256, 0, stream>>>(h, dinv, tlist, cur, ebuf, ucount,
                                               ocnt, olist, out);
}